// Round 1
// baseline (217.649 us; speedup 1.0000x reference)
//
#include <hip/hip_runtime.h>
#include <stdint.h>

typedef __attribute__((ext_vector_type(4))) float f32x4;
typedef __attribute__((ext_vector_type(8))) short bf16x8;

#define C_NORM_LOG2E 0.18033688011112043f

__device__ __forceinline__ uint32_t swz(uint32_t a) { return a ^ (((a >> 7) & 7u) << 4); }

__device__ __forceinline__ uint32_t cvt_pk_bf16(float a, float b) {
  uint32_t r;
  asm("v_cvt_pk_bf16_f32 %0, %1, %2" : "=v"(r) : "v"(a), "v"(b));
  return r;
}

__device__ __forceinline__ ushort f2bf(float f) {
  uint32_t u = __float_as_uint(f);
  u += 0x7FFFu + ((u >> 16) & 1u);
  return (ushort)(u >> 16);
}

// ---------------- pack W: [192][512] bf16, rows 0-63=Wq, 64-127=Wk, 128-191=Wv ----------------
__global__ void pack_w_kernel(const float* __restrict__ Wk, const float* __restrict__ Wq,
                              const float* __restrict__ Wv, ushort* __restrict__ Wp) {
  int i = blockIdx.x * 256 + threadIdx.x;  // 192*512 = 98304, grid 384
  int n = i >> 9, e = i & 511;
  float val;
  if (n < 64)       val = Wq[n * 512 + e];
  else if (n < 128) val = Wk[(n - 64) * 512 + e];
  else              val = Wv[(n - 128) * 512 + e];
  Wp[i] = f2bf(val);
}

// ---------------- pack PE: PEd[n][m] = PE[2n][2m] * NORM*log2e, f32 [512][512] ----------------
__global__ void pack_pe_kernel(const float* __restrict__ PE, float* __restrict__ PEd) {
  int i = blockIdx.x * 256 + threadIdx.x;  // 262144, grid 1024
  int n = i >> 9, m = i & 511;
  PEd[i] = PE[n * 2048 + m * 2] * C_NORM_LOG2E;
}

// ---------------- projection: QKV[r][d] bf16, r = (b*16+s)*512 + m, from x[b, 32m+s, :] ----------
__global__ __launch_bounds__(512, 2) void proj_kernel(
    const float* __restrict__ x, const ushort* __restrict__ Wp,
    ushort* __restrict__ Qw, ushort* __restrict__ Kw, ushort* __restrict__ Vw) {
  __shared__ char Xl[32768];  // 256 rows x 64 bf16, swizzled
  const int tid = threadIdx.x;
  const int w = tid >> 6, lane = tid & 63, g = lane >> 4, l15 = lane & 15;
  const int wr = w >> 2, wc = w & 3;  // 2x4 wave grid: 128 rows x 48 cols each
  const int R0 = blockIdx.x * 256;
  const int b = R0 >> 13, s = (R0 >> 9) & 15, m0 = R0 & 511;
  const float* xb = x + (size_t)b * 8388608 + (size_t)s * 512;

  f32x4 acc[8][3];
#pragma unroll
  for (int i = 0; i < 8; ++i)
#pragma unroll
    for (int j = 0; j < 3; ++j) acc[i][j] = (f32x4){0.f, 0.f, 0.f, 0.f};

  for (int kt = 0; kt < 8; ++kt) {
    const int k0 = kt * 64;
    __syncthreads();
    // stage X tile: 256 rows x 64 f32 -> bf16 LDS (4 thr/row, 2 passes)
#pragma unroll
    for (int p = 0; p < 2; ++p) {
      int rl = p * 128 + (tid >> 2);
      int c4 = tid & 3;
      const float* src = xb + (size_t)(m0 + rl) * 16384 + k0 + c4 * 4;
      uint32_t lb = rl * 128 + c4 * 8;
#pragma unroll
      for (int j = 0; j < 4; ++j) {
        float4 f = *(const float4*)(src + j * 16);
        uint2 u;
        u.x = cvt_pk_bf16(f.x, f.y);
        u.y = cvt_pk_bf16(f.z, f.w);
        *(uint2*)(Xl + swz(lb + j * 32)) = u;
      }
    }
    __syncthreads();
    // compute: A from LDS X, B straight from global Wp (L2-hot)
#pragma unroll
    for (int kd = 0; kd < 2; ++kd) {
      bf16x8 a[8], bb[3];
#pragma unroll
      for (int i = 0; i < 8; ++i)
        a[i] = *(const bf16x8*)(Xl + swz((wr * 128 + i * 16 + l15) * 128 + kd * 64 + g * 16));
#pragma unroll
      for (int j = 0; j < 3; ++j)
        bb[j] = *(const bf16x8*)((const char*)Wp + (size_t)(wc * 48 + j * 16 + l15) * 1024 +
                                 k0 * 2 + kd * 64 + g * 16);
#pragma unroll
      for (int i = 0; i < 8; ++i)
#pragma unroll
        for (int j = 0; j < 3; ++j)
          acc[i][j] = __builtin_amdgcn_mfma_f32_16x16x32_bf16(a[i], bb[j], acc[i][j], 0, 0, 0);
    }
  }
  // epilogue: D layout col = l15 (n), row = g*4 + r
#pragma unroll
  for (int i = 0; i < 8; ++i) {
    int rl = wr * 128 + i * 16 + g * 4;
    size_t rbase = (size_t)(R0 + rl) * 64;
#pragma unroll
    for (int j = 0; j < 3; ++j) {
      int n = wc * 48 + j * 16 + l15;
      int sel = n >> 6, d = n & 63;
      ushort* dst = (sel == 0) ? Qw : (sel == 1) ? Kw : Vw;
      dst += rbase + d;
#pragma unroll
      for (int r = 0; r < 4; ++r) dst[(size_t)r * 64] = f2bf(acc[i][j][r]);
    }
  }
}

// ---------------- attention per (b,s): S=K.Q^T, mask(n>=m)+bias, softmax over m, att=P^T.V ------
__global__ __launch_bounds__(512, 2) void attn_kernel(
    const ushort* __restrict__ Qw, const ushort* __restrict__ Kw,
    const ushort* __restrict__ Vw, const float* __restrict__ PEd,
    float* __restrict__ out) {
  __shared__ char Vtl[8192];    // V^T tile [64 d][64 n] bf16, swizzled
  __shared__ char Ptl[65536];   // per-wave P^T [64 m][64 n] bf16, swizzled
  __shared__ float red[64 * 8];
  __shared__ float Mrow[64];
  __shared__ float rZrow[64];

  const int tid = threadIdx.x;
  const int w = tid >> 6, lane = tid & 63, g = lane >> 4, l15 = lane & 15;
  const int bs = blockIdx.x;           // b*16 + s
  const size_t base = (size_t)bs * 32768;  // elements into Q/K/V
  const int wm0 = w * 64;              // wave's m slice

  // persistent Q fragments (B operand): col m = l15, k(d) = kd*32 + g*8 + e
  bf16x8 bQ[4][2];
#pragma unroll
  for (int mf = 0; mf < 4; ++mf)
#pragma unroll
    for (int kd = 0; kd < 2; ++kd)
      bQ[mf][kd] = *(const bf16x8*)((const char*)(Qw + base) +
                                    (size_t)(wm0 + mf * 16 + l15) * 128 + kd * 64 + g * 16);

  f32x4 att[4][4];
#pragma unroll
  for (int i = 0; i < 4; ++i)
#pragma unroll
    for (int j = 0; j < 4; ++j) att[i][j] = (f32x4){0.f, 0.f, 0.f, 0.f};

  for (int nt = 0; nt < 8; ++nt) {
    // stage V^T (transpose V tile into LDS)
    {
      int row = tid >> 3, seg = tid & 7;  // row = n-local, seg*8 = d0
      const char* vb = (const char*)(Vw + base) + nt * 8192;
      uint4 dv = *(const uint4*)(vb + row * 128 + seg * 16);
      uint32_t dw[4] = {dv.x, dv.y, dv.z, dv.w};
#pragma unroll
      for (int t = 0; t < 4; ++t) {
        int d0 = seg * 8 + t * 2;
        *(ushort*)(Vtl + swz((uint32_t)(d0 * 128 + row * 2))) = (ushort)(dw[t] & 0xffffu);
        *(ushort*)(Vtl + swz((uint32_t)((d0 + 1) * 128 + row * 2))) = (ushort)(dw[t] >> 16);
      }
    }
    __syncthreads();

    // QK^T: A = K frags from global (L2-hot), B = persistent Q frags
    f32x4 S[4][4];
#pragma unroll
    for (int nf = 0; nf < 4; ++nf) {
      bf16x8 aK[2];
#pragma unroll
      for (int kd = 0; kd < 2; ++kd)
        aK[kd] = *(const bf16x8*)((const char*)(Kw + base) + nt * 8192 +
                                  (size_t)(nf * 16 + l15) * 128 + kd * 64 + g * 16);
#pragma unroll
      for (int mf = 0; mf < 4; ++mf) {
        f32x4 c = (f32x4){0.f, 0.f, 0.f, 0.f};
        c = __builtin_amdgcn_mfma_f32_16x16x32_bf16(aK[0], bQ[mf][0], c, 0, 0, 0);
        c = __builtin_amdgcn_mfma_f32_16x16x32_bf16(aK[1], bQ[mf][1], c, 0, 0, 0);
        S[nf][mf] = c;
      }
    }

    // mask (keep n>=m) + positional bias (pre-scaled) + scale; D layout: col m=l15, row n=g*4+r
#pragma unroll
    for (int nf = 0; nf < 4; ++nf) {
      int nb = nt * 64 + nf * 16 + g * 4;
#pragma unroll
      for (int mf = 0; mf < 4; ++mf) {
        int m_ = wm0 + mf * 16 + l15;
        const float* pp = PEd + (size_t)nb * 512 + m_;
#pragma unroll
        for (int r = 0; r < 4; ++r) {
          float L = ((nb + r) >= m_) ? fmaf(S[nf][mf][r], C_NORM_LOG2E, pp[(size_t)r * 512])
                                     : -INFINITY;
          S[nf][mf][r] = L;
        }
      }
    }

    // row max over m: lane-local over mf, butterfly over 16 lanes, LDS over 8 waves
    float lm[4][4];
#pragma unroll
    for (int nf = 0; nf < 4; ++nf)
#pragma unroll
      for (int r = 0; r < 4; ++r)
        lm[nf][r] = fmaxf(fmaxf(S[nf][0][r], S[nf][1][r]), fmaxf(S[nf][2][r], S[nf][3][r]));
#pragma unroll
    for (int msk = 1; msk < 16; msk <<= 1)
#pragma unroll
      for (int nf = 0; nf < 4; ++nf)
#pragma unroll
        for (int r = 0; r < 4; ++r)
          lm[nf][r] = fmaxf(lm[nf][r], __shfl_xor(lm[nf][r], msk, 16));
    if (l15 == 0) {
#pragma unroll
      for (int nf = 0; nf < 4; ++nf)
#pragma unroll
        for (int r = 0; r < 4; ++r) red[(nf * 16 + g * 4 + r) * 8 + w] = lm[nf][r];
    }
    __syncthreads();
    if (tid < 64) {
      float mx = red[tid * 8];
#pragma unroll
      for (int j = 1; j < 8; ++j) mx = fmaxf(mx, red[tid * 8 + j]);
      Mrow[tid] = mx;
    }
    __syncthreads();

    // exp2 + row sum
    float ls[4][4];
#pragma unroll
    for (int nf = 0; nf < 4; ++nf)
#pragma unroll
      for (int r = 0; r < 4; ++r) {
        float M = Mrow[nf * 16 + g * 4 + r];
        float s0 = 0.f;
#pragma unroll
        for (int mf = 0; mf < 4; ++mf) {
          float pv = exp2f(S[nf][mf][r] - M);
          S[nf][mf][r] = pv;
          s0 += pv;
        }
        ls[nf][r] = s0;
      }
#pragma unroll
    for (int msk = 1; msk < 16; msk <<= 1)
#pragma unroll
      for (int nf = 0; nf < 4; ++nf)
#pragma unroll
        for (int r = 0; r < 4; ++r) ls[nf][r] += __shfl_xor(ls[nf][r], msk, 16);
    if (l15 == 0) {
#pragma unroll
      for (int nf = 0; nf < 4; ++nf)
#pragma unroll
        for (int r = 0; r < 4; ++r) red[(nf * 16 + g * 4 + r) * 8 + w] = ls[nf][r];
    }
    __syncthreads();
    if (tid < 64) {
      float z = red[tid * 8];
#pragma unroll
      for (int j = 1; j < 8; ++j) z += red[tid * 8 + j];
      rZrow[tid] = 1.0f / z;
    }
    __syncthreads();

    // normalize, pack bf16, write own-wave P^T [m][n] to LDS
    float rz[4][4];
#pragma unroll
    for (int nf = 0; nf < 4; ++nf)
#pragma unroll
      for (int r = 0; r < 4; ++r) rz[nf][r] = rZrow[nf * 16 + g * 4 + r];
#pragma unroll
    for (int nf = 0; nf < 4; ++nf)
#pragma unroll
      for (int mf = 0; mf < 4; ++mf) {
        uint2 u;
        u.x = cvt_pk_bf16(S[nf][mf][0] * rz[nf][0], S[nf][mf][1] * rz[nf][1]);
        u.y = cvt_pk_bf16(S[nf][mf][2] * rz[nf][2], S[nf][mf][3] * rz[nf][3]);
        *(uint2*)(Ptl + w * 8192 + swz((uint32_t)((mf * 16 + l15) * 128 + nf * 32 + g * 8))) = u;
      }

    // P^T V: A = own P^T frags, B = V^T frags (same-wave LDS RAW, in-order DS pipe)
#pragma unroll
    for (int kf = 0; kf < 2; ++kf) {
      bf16x8 aP[4], bV[4];
#pragma unroll
      for (int mf = 0; mf < 4; ++mf)
        aP[mf] = *(const bf16x8*)(Ptl + w * 8192 +
                                  swz((uint32_t)((mf * 16 + l15) * 128 + kf * 64 + g * 16)));
#pragma unroll
      for (int df = 0; df < 4; ++df)
        bV[df] = *(const bf16x8*)(Vtl + swz((uint32_t)((df * 16 + l15) * 128 + kf * 64 + g * 16)));
#pragma unroll
      for (int mf = 0; mf < 4; ++mf)
#pragma unroll
        for (int df = 0; df < 4; ++df)
          att[mf][df] = __builtin_amdgcn_mfma_f32_16x16x32_bf16(aP[mf], bV[df], att[mf][df], 0, 0, 0);
    }
    __syncthreads();
  }

  // epilogue: out[b, 2*(s*512+m), d] = att; out[b, odd, d] = 0
  const int b = bs >> 4, s = bs & 15;
  float* ob = out + (size_t)b * 1048576;
#pragma unroll
  for (int mf = 0; mf < 4; ++mf)
#pragma unroll
    for (int df = 0; df < 4; ++df)
#pragma unroll
      for (int r = 0; r < 4; ++r) {
        int m_ = wm0 + mf * 16 + g * 4 + r;
        size_t t0 = 2 * ((size_t)s * 512 + m_);
        ob[t0 * 64 + df * 16 + l15] = att[mf][df][r];
        ob[(t0 + 1) * 64 + df * 16 + l15] = 0.f;
      }
}

extern "C" void kernel_launch(void* const* d_in, const int* in_sizes, int n_in,
                              void* d_out, int out_size, void* d_ws, size_t ws_size,
                              hipStream_t stream) {
  const float* x  = (const float*)d_in[0];
  const float* Wk = (const float*)d_in[1];
  const float* Wq = (const float*)d_in[2];
  const float* Wv = (const float*)d_in[3];
  const float* PE = (const float*)d_in[4];
  float* out = (float*)d_out;
  char* ws = (char*)d_ws;

  ushort* Qw = (ushort*)(ws);               // 65536*64*2 = 8 MB
  ushort* Kw = (ushort*)(ws + 8388608);     // 8 MB
  ushort* Vw = (ushort*)(ws + 16777216);    // 8 MB
  ushort* Wp = (ushort*)(ws + 25165824);    // 192 KB
  float*  PEd = (float*)(ws + 25362432);    // 1 MB

  pack_w_kernel<<<dim3(384), dim3(256), 0, stream>>>(Wk, Wq, Wv, Wp);
  pack_pe_kernel<<<dim3(1024), dim3(256), 0, stream>>>(PE, PEd);
  proj_kernel<<<dim3(256), dim3(512), 0, stream>>>(x, Wp, Qw, Kw, Vw);
  attn_kernel<<<dim3(128), dim3(512), 0, stream>>>(Qw, Kw, Vw, PEd, out);
}

// Round 2
// 135.515 us; speedup vs baseline: 1.6061x; 1.6061x over previous
//
#include <hip/hip_runtime.h>
#include <stdint.h>

typedef __attribute__((ext_vector_type(4))) float f32x4;
typedef __attribute__((ext_vector_type(8))) short bf16x8;

#define C_NORM_LOG2E 0.18033688011112043f

__device__ __forceinline__ uint32_t swz(uint32_t a) { return a ^ (((a >> 7) & 7u) << 4); }

__device__ __forceinline__ uint32_t cvt_pk_bf16(float a, float b) {
  uint32_t r;
  asm("v_cvt_pk_bf16_f32 %0, %1, %2" : "=v"(r) : "v"(a), "v"(b));
  return r;
}

__device__ __forceinline__ ushort f2bf(float f) {
  uint32_t u = __float_as_uint(f);
  u += 0x7FFFu + ((u >> 16) & 1u);
  return (ushort)(u >> 16);
}

// ---------------- pack W: [192][512] bf16, rows 0-63=Wq, 64-127=Wk, 128-191=Wv ----------------
__global__ void pack_w_kernel(const float* __restrict__ Wk, const float* __restrict__ Wq,
                              const float* __restrict__ Wv, ushort* __restrict__ Wp) {
  int i = blockIdx.x * 256 + threadIdx.x;  // 192*512 = 98304, grid 384
  int n = i >> 9, e = i & 511;
  float val;
  if (n < 64)       val = Wq[n * 512 + e];
  else if (n < 128) val = Wk[(n - 64) * 512 + e];
  else              val = Wv[(n - 128) * 512 + e];
  Wp[i] = f2bf(val);
}

// ---------------- pack PE transposed: PEdT[m][n] = PE[2n][2m] * NORM*log2e, f32 [512][512] -----
__global__ void pack_pe_kernel(const float* __restrict__ PE, float* __restrict__ PEdT) {
  int i = blockIdx.x * 256 + threadIdx.x;  // 262144, grid 1024
  int m = i >> 9, n = i & 511;
  PEdT[i] = PE[n * 2048 + m * 2] * C_NORM_LOG2E;
}

// ---------------- projection: QKV[r][d] bf16, r = (b*16+s)*512 + m, from x[b, 32m+s, :] ----------
__global__ __launch_bounds__(512, 2) void proj_kernel(
    const float* __restrict__ x, const ushort* __restrict__ Wp,
    ushort* __restrict__ Qw, ushort* __restrict__ Kw, ushort* __restrict__ Vw) {
  __shared__ char Xl[16384];  // 128 rows x 64 bf16, swizzled
  const int tid = threadIdx.x;
  const int w = tid >> 6, lane = tid & 63, g = lane >> 4, l15 = lane & 15;
  const int wr = w >> 2, wc = w & 3;  // 2x4 wave grid: 64 rows x 48 cols each
  const int R0 = blockIdx.x * 128;    // grid 512
  const int b = R0 >> 13, s = (R0 >> 9) & 15, m0 = R0 & 511;
  const float* xb = x + (size_t)b * 8388608 + (size_t)s * 512;

  f32x4 acc[4][3];
#pragma unroll
  for (int i = 0; i < 4; ++i)
#pragma unroll
    for (int j = 0; j < 3; ++j) acc[i][j] = (f32x4){0.f, 0.f, 0.f, 0.f};

  for (int kt = 0; kt < 8; ++kt) {
    const int k0 = kt * 64;
    __syncthreads();
    // stage X tile: 128 rows x 64 f32 -> bf16 LDS (4 thr/row)
    {
      int rl = tid >> 2;
      int c4 = tid & 3;
      const float* src = xb + (size_t)(m0 + rl) * 16384 + k0 + c4 * 4;
      uint32_t lb = rl * 128 + c4 * 8;
#pragma unroll
      for (int j = 0; j < 4; ++j) {
        float4 f = *(const float4*)(src + j * 16);
        uint2 u;
        u.x = cvt_pk_bf16(f.x, f.y);
        u.y = cvt_pk_bf16(f.z, f.w);
        *(uint2*)(Xl + swz(lb + j * 32)) = u;
      }
    }
    __syncthreads();
    // compute: A from LDS X, B straight from global Wp (L2-hot)
#pragma unroll
    for (int kd = 0; kd < 2; ++kd) {
      bf16x8 a[4], bb[3];
#pragma unroll
      for (int i = 0; i < 4; ++i)
        a[i] = *(const bf16x8*)(Xl + swz((wr * 64 + i * 16 + l15) * 128 + kd * 64 + g * 16));
#pragma unroll
      for (int j = 0; j < 3; ++j)
        bb[j] = *(const bf16x8*)((const char*)Wp + (size_t)(wc * 48 + j * 16 + l15) * 1024 +
                                 k0 * 2 + kd * 64 + g * 16);
#pragma unroll
      for (int i = 0; i < 4; ++i)
#pragma unroll
        for (int j = 0; j < 3; ++j)
          acc[i][j] = __builtin_amdgcn_mfma_f32_16x16x32_bf16(a[i], bb[j], acc[i][j], 0, 0, 0);
    }
  }
  // epilogue: D layout col = l15 (n), row = g*4 + r
#pragma unroll
  for (int i = 0; i < 4; ++i) {
    int rl = wr * 64 + i * 16 + g * 4;
    size_t rbase = (size_t)(R0 + rl) * 64;
#pragma unroll
    for (int j = 0; j < 3; ++j) {
      int n = wc * 48 + j * 16 + l15;
      int sel = n >> 6, d = n & 63;
      ushort* dst = (sel == 0) ? Qw : (sel == 1) ? Kw : Vw;
      dst += rbase + d;
#pragma unroll
      for (int r = 0; r < 4; ++r) dst[(size_t)r * 64] = f2bf(acc[i][j][r]);
    }
  }
}

// ------- attention, chunked over n: block = (bs, c), rows n in [128c,128c+128) -------
// S=K.Q^T, mask(n>=m)+bias, softmax over m (rows n), partial att^c = P^T.V -> bf16 partials
__global__ __launch_bounds__(512, 2) void attn_kernel(
    const ushort* __restrict__ Qw, const ushort* __restrict__ Kw,
    const ushort* __restrict__ Vw, const float* __restrict__ PEdT,
    ushort* __restrict__ Pp) {
  __shared__ char Vtl[8192];    // V^T tile [64 d][64 n] bf16, swizzled
  __shared__ char Ptl[65536];   // per-wave P^T [64 m][64 n] bf16, swizzled
  __shared__ float red[64 * 8];
  __shared__ float Mrow[64];
  __shared__ float rZrow[64];

  const int tid = threadIdx.x;
  const int w = tid >> 6, lane = tid & 63, g = lane >> 4, l15 = lane & 15;
  const int bid = blockIdx.x;
  const int bs = bid >> 2, c = bid & 3;    // 128 bs x 4 chunks
  const size_t base = (size_t)bs * 32768;  // elements into Q/K/V
  const int wm0 = w * 64;                  // wave's m slice
  const bool active = (wm0 < 128 * (c + 1));  // masked-out waves skip compute

  // persistent Q fragments (B operand): col m = l15, k(d) = kd*32 + g*8 + e
  bf16x8 bQ[4][2];
  if (active) {
#pragma unroll
    for (int mf = 0; mf < 4; ++mf)
#pragma unroll
      for (int kd = 0; kd < 2; ++kd)
        bQ[mf][kd] = *(const bf16x8*)((const char*)(Qw + base) +
                                      (size_t)(wm0 + mf * 16 + l15) * 128 + kd * 64 + g * 16);
  }

  f32x4 att[4][4];
#pragma unroll
  for (int i = 0; i < 4; ++i)
#pragma unroll
    for (int j = 0; j < 4; ++j) att[i][j] = (f32x4){0.f, 0.f, 0.f, 0.f};

  for (int it = 0; it < 2; ++it) {
    const int nt = 2 * c + it;
    // stage V^T (transpose V tile into LDS) -- all threads
    {
      int row = tid >> 3, seg = tid & 7;  // row = n-local, seg*8 = d0
      const char* vb = (const char*)(Vw + base) + nt * 8192;
      uint4 dv = *(const uint4*)(vb + row * 128 + seg * 16);
      uint32_t dw[4] = {dv.x, dv.y, dv.z, dv.w};
#pragma unroll
      for (int t = 0; t < 4; ++t) {
        int d0 = seg * 8 + t * 2;
        *(ushort*)(Vtl + swz((uint32_t)(d0 * 128 + row * 2))) = (ushort)(dw[t] & 0xffffu);
        *(ushort*)(Vtl + swz((uint32_t)((d0 + 1) * 128 + row * 2))) = (ushort)(dw[t] >> 16);
      }
    }
    __syncthreads();

    f32x4 S[4][4];
    float lm[4][4];
    if (active) {
      // QK^T: A = K frags from global (L2-hot), B = persistent Q frags
#pragma unroll
      for (int nf = 0; nf < 4; ++nf) {
        bf16x8 aK[2];
#pragma unroll
        for (int kd = 0; kd < 2; ++kd)
          aK[kd] = *(const bf16x8*)((const char*)(Kw + base) + nt * 8192 +
                                    (size_t)(nf * 16 + l15) * 128 + kd * 64 + g * 16);
#pragma unroll
        for (int mf = 0; mf < 4; ++mf) {
          f32x4 cc = (f32x4){0.f, 0.f, 0.f, 0.f};
          cc = __builtin_amdgcn_mfma_f32_16x16x32_bf16(aK[0], bQ[mf][0], cc, 0, 0, 0);
          cc = __builtin_amdgcn_mfma_f32_16x16x32_bf16(aK[1], bQ[mf][1], cc, 0, 0, 0);
          S[nf][mf] = cc;
        }
      }
      // mask (keep n>=m) + positional bias (transposed, float4); D: col m=l15, row n=g*4+r
#pragma unroll
      for (int nf = 0; nf < 4; ++nf) {
        int nb = nt * 64 + nf * 16 + g * 4;
#pragma unroll
        for (int mf = 0; mf < 4; ++mf) {
          int m_ = wm0 + mf * 16 + l15;
          f32x4 pe = *(const f32x4*)(PEdT + (size_t)m_ * 512 + nb);
#pragma unroll
          for (int r = 0; r < 4; ++r)
            S[nf][mf][r] = ((nb + r) >= m_) ? fmaf(S[nf][mf][r], C_NORM_LOG2E, pe[r]) : -INFINITY;
        }
      }
      // row max over m: lane-local over mf, butterfly over 16 lanes
#pragma unroll
      for (int nf = 0; nf < 4; ++nf)
#pragma unroll
        for (int r = 0; r < 4; ++r)
          lm[nf][r] = fmaxf(fmaxf(S[nf][0][r], S[nf][1][r]), fmaxf(S[nf][2][r], S[nf][3][r]));
#pragma unroll
      for (int msk = 1; msk < 16; msk <<= 1)
#pragma unroll
        for (int nf = 0; nf < 4; ++nf)
#pragma unroll
          for (int r = 0; r < 4; ++r)
            lm[nf][r] = fmaxf(lm[nf][r], __shfl_xor(lm[nf][r], msk, 16));
    } else {
#pragma unroll
      for (int nf = 0; nf < 4; ++nf)
#pragma unroll
        for (int r = 0; r < 4; ++r) lm[nf][r] = -INFINITY;
    }
    if (l15 == 0) {
#pragma unroll
      for (int nf = 0; nf < 4; ++nf)
#pragma unroll
        for (int r = 0; r < 4; ++r) red[(nf * 16 + g * 4 + r) * 8 + w] = lm[nf][r];
    }
    __syncthreads();
    if (tid < 64) {
      float mx = red[tid * 8];
#pragma unroll
      for (int j = 1; j < 8; ++j) mx = fmaxf(mx, red[tid * 8 + j]);
      Mrow[tid] = mx;
    }
    __syncthreads();

    // exp2 + row sum
    float ls[4][4];
    if (active) {
#pragma unroll
      for (int nf = 0; nf < 4; ++nf)
#pragma unroll
        for (int r = 0; r < 4; ++r) {
          float M = Mrow[nf * 16 + g * 4 + r];
          float s0 = 0.f;
#pragma unroll
          for (int mf = 0; mf < 4; ++mf) {
            float pv = exp2f(S[nf][mf][r] - M);
            S[nf][mf][r] = pv;
            s0 += pv;
          }
          ls[nf][r] = s0;
        }
#pragma unroll
      for (int msk = 1; msk < 16; msk <<= 1)
#pragma unroll
        for (int nf = 0; nf < 4; ++nf)
#pragma unroll
          for (int r = 0; r < 4; ++r) ls[nf][r] += __shfl_xor(ls[nf][r], msk, 16);
    } else {
#pragma unroll
      for (int nf = 0; nf < 4; ++nf)
#pragma unroll
        for (int r = 0; r < 4; ++r) ls[nf][r] = 0.f;
    }
    if (l15 == 0) {
#pragma unroll
      for (int nf = 0; nf < 4; ++nf)
#pragma unroll
        for (int r = 0; r < 4; ++r) red[(nf * 16 + g * 4 + r) * 8 + w] = ls[nf][r];
    }
    __syncthreads();
    if (tid < 64) {
      float z = red[tid * 8];
#pragma unroll
      for (int j = 1; j < 8; ++j) z += red[tid * 8 + j];
      rZrow[tid] = 1.0f / z;
    }
    __syncthreads();

    if (active) {
      // normalize, pack bf16, write own-wave P^T [m][n] to LDS
      float rz[4][4];
#pragma unroll
      for (int nf = 0; nf < 4; ++nf)
#pragma unroll
        for (int r = 0; r < 4; ++r) rz[nf][r] = rZrow[nf * 16 + g * 4 + r];
#pragma unroll
      for (int nf = 0; nf < 4; ++nf)
#pragma unroll
        for (int mf = 0; mf < 4; ++mf) {
          uint2 u;
          u.x = cvt_pk_bf16(S[nf][mf][0] * rz[nf][0], S[nf][mf][1] * rz[nf][1]);
          u.y = cvt_pk_bf16(S[nf][mf][2] * rz[nf][2], S[nf][mf][3] * rz[nf][3]);
          *(uint2*)(Ptl + w * 8192 + swz((uint32_t)((mf * 16 + l15) * 128 + nf * 32 + g * 8))) = u;
        }
      // P^T V: A = own P^T frags, B = V^T frags
#pragma unroll
      for (int kf = 0; kf < 2; ++kf) {
        bf16x8 aP[4], bV[4];
#pragma unroll
        for (int mf = 0; mf < 4; ++mf)
          aP[mf] = *(const bf16x8*)(Ptl + w * 8192 +
                                    swz((uint32_t)((mf * 16 + l15) * 128 + kf * 64 + g * 16)));
#pragma unroll
        for (int df = 0; df < 4; ++df)
          bV[df] = *(const bf16x8*)(Vtl + swz((uint32_t)((df * 16 + l15) * 128 + kf * 64 + g * 16)));
#pragma unroll
        for (int mf = 0; mf < 4; ++mf)
#pragma unroll
          for (int df = 0; df < 4; ++df)
            att[mf][df] =
                __builtin_amdgcn_mfma_f32_16x16x32_bf16(aP[mf], bV[df], att[mf][df], 0, 0, 0);
      }
    }
    __syncthreads();
  }

  // epilogue: write bf16 partial att^c at Pp[(c*128+bs)*32768 + m*64 + d]
  ushort* pb = Pp + ((size_t)c * 128 + bs) * 32768;
  if (active) {
#pragma unroll
    for (int mf = 0; mf < 4; ++mf)
#pragma unroll
      for (int df = 0; df < 4; ++df)
#pragma unroll
        for (int r = 0; r < 4; ++r) {
          int m_ = wm0 + mf * 16 + g * 4 + r;
          pb[(size_t)m_ * 64 + df * 16 + l15] = f2bf(att[mf][df][r]);
        }
  } else {
    // zero this wave's 64x64 slice (ws is poisoned, reduce reads all chunks)
    uint4 z = (uint4){0u, 0u, 0u, 0u};
    char* zb = (char*)(pb + (size_t)wm0 * 64);
#pragma unroll
    for (int k = 0; k < 8; ++k) *(uint4*)(zb + k * 1024 + lane * 16) = z;
  }
}

// ---------------- reduce: out[b,2m',d] = sum_c partial, out[b,odd,d] = 0 ----------------
__global__ void reduce_kernel(const ushort* __restrict__ Pp, float* __restrict__ out) {
  int jj = blockIdx.x * 256 + threadIdx.x;  // 524288 threads, grid 2048
  int d8 = jj & 7, m = (jj >> 3) & 511, bs = jj >> 12;
  const size_t ji = ((size_t)bs * 512 + m) * 64 + d8 * 8;
  float f[8];
#pragma unroll
  for (int e = 0; e < 8; ++e) f[e] = 0.f;
#pragma unroll
  for (int c = 0; c < 4; ++c) {
    uint4 v = *(const uint4*)(Pp + (size_t)c * 4194304 + ji);
    uint32_t dw[4] = {v.x, v.y, v.z, v.w};
#pragma unroll
    for (int t = 0; t < 4; ++t) {
      f[t * 2] += __uint_as_float(dw[t] << 16);
      f[t * 2 + 1] += __uint_as_float(dw[t] & 0xffff0000u);
    }
  }
  int b = bs >> 4, s = bs & 15;
  size_t t0 = 2 * ((size_t)s * 512 + m);
  float* ob = out + (size_t)b * 1048576 + t0 * 64 + d8 * 8;
  *(float4*)(ob) = (float4){f[0], f[1], f[2], f[3]};
  *(float4*)(ob + 4) = (float4){f[4], f[5], f[6], f[7]};
  *(float4*)(ob + 64) = (float4){0.f, 0.f, 0.f, 0.f};
  *(float4*)(ob + 68) = (float4){0.f, 0.f, 0.f, 0.f};
}

extern "C" void kernel_launch(void* const* d_in, const int* in_sizes, int n_in,
                              void* d_out, int out_size, void* d_ws, size_t ws_size,
                              hipStream_t stream) {
  const float* x  = (const float*)d_in[0];
  const float* Wk = (const float*)d_in[1];
  const float* Wq = (const float*)d_in[2];
  const float* Wv = (const float*)d_in[3];
  const float* PE = (const float*)d_in[4];
  float* out = (float*)d_out;
  char* ws = (char*)d_ws;

  ushort* Qw  = (ushort*)(ws);              // 8 MB
  ushort* Kw  = (ushort*)(ws + 8388608);    // 8 MB
  ushort* Vw  = (ushort*)(ws + 16777216);   // 8 MB
  ushort* Wp  = (ushort*)(ws + 25165824);   // 192 KB
  float*  PEdT = (float*)(ws + 25362432);   // 1 MB
  ushort* Pp  = (ushort*)(ws + 33554432);   // 32 MB partials (4 chunks)

  pack_w_kernel<<<dim3(384), dim3(256), 0, stream>>>(Wk, Wq, Wv, Wp);
  pack_pe_kernel<<<dim3(1024), dim3(256), 0, stream>>>(PE, PEdT);
  proj_kernel<<<dim3(512), dim3(512), 0, stream>>>(x, Wp, Qw, Kw, Vw);
  attn_kernel<<<dim3(512), dim3(512), 0, stream>>>(Qw, Kw, Vw, PEdT, Pp);
  reduce_kernel<<<dim3(2048), dim3(256), 0, stream>>>(Pp, out);
}